// Round 4
// baseline (1157.599 us; speedup 1.0000x reference)
//
#include <hip/hip_runtime.h>
#include <hip/hip_bf16.h>

#define L_DIM 16384
#define C_DIM 256
#define NV 8
#define NH 4
#define DH 64
#define TL 8          // l's per block
#define NTHREADS 512  // 8 waves

// LDS row strides (all chosen: non-zero residue mod 32 banks, 16B-aligned rows)
#define QKPAD 132     // fp32 rows for q|k   (132 % 32 = 4)
#define VPAD 72       // bf16 rows for v     (36 words % 32 = 4; 144 B rows, 16B-aligned)
#define WPAD 264      // bf16 rows for ctx/att (132 words % 32 = 4; 528 B rows)
#define GPAD 65       // fp32 rows for g1s   (65 % 32 = 1)

typedef __attribute__((ext_vector_type(8))) short bf16x8;
typedef __attribute__((ext_vector_type(4))) float f32x4;

__device__ inline float bf2f(short s){
  union { unsigned u; float f; } v; v.u = ((unsigned)(unsigned short)s) << 16; return v.f;
}
__device__ inline short f2bf(float f){
  __hip_bfloat16 h = __float2bfloat16(f);
  union { __hip_bfloat16 h; short s; } v; v.h = h; return v.s;
}

// ---------------- prep: view_info + bf16 weight conversion ----------------
__global__ void prep_kernel(const float* __restrict__ vw, const float* __restrict__ vb,
                            const float* __restrict__ w_in, const float* __restrict__ w_out,
                            const float* __restrict__ w_g1,
                            float* __restrict__ view_info, short* __restrict__ win_hi,
                            short* __restrict__ win_lo, short* __restrict__ wout_b,
                            short* __restrict__ wg1_b){
  int tid = threadIdx.x, bid = blockIdx.x;
  if (bid == 0){
    int c = tid;                       // 256 threads, one channel each
    float rs = 0.f;
    for (int k = 0; k < C_DIM; k++) rs += vw[c*C_DIM + k];
    float b = vb[c];
    for (int n = 0; n < NV; n++) view_info[n*C_DIM + c] = (n * 0.125f) * rs + b;
  }
  int gid = bid * blockDim.x + tid;
  int stride = gridDim.x * blockDim.x;
  const int NIN = 768*256, NOUT = 256*256, NG = 64*256;
  for (int i = gid; i < NIN + NOUT + NG; i += stride){
    if (i < NIN){
      float v = w_in[i]; short hi = f2bf(v);
      win_hi[i] = hi; win_lo[i] = f2bf(v - bf2f(hi));
    } else if (i < NIN + NOUT){
      wout_b[i - NIN] = f2bf(w_out[i - NIN]);
    } else {
      wg1_b[i - NIN - NOUT] = f2bf(w_g1[i - NIN - NOUT]);
    }
  }
}

// ---------------- fused main kernel: one block = 8 l's (64 tokens) ----------------
// W is NOT staged in LDS: B-fragments load straight from global (L1/L2-resident)
// into VGPRs -> no staging barriers, no LDS W traffic.
// __launch_bounds__(512,2): cap at 128 VGPR / 2 blocks-CU semantics. (512,4)
// capped VGPRs at 64 -> 138 MB of scratch spills, 2x regression (round 3).
// LDS carve (dynamic, 79424 B -> 2 blocks/CU):
//   [0,33792)       qk  : fp32 [64][QKPAD]  q cols 0-63, k cols 64-127 (per head)
//                   att : bf16 [64][WPAD]   (overlays qk after attention done)
//   [33792,43008)   v   : bf16 [64][VPAD]   (per head)
//   [43008,76800)   ctx : bf16 [64][WPAD]
//                   g1s : fp32 [64][GPAD]   (overlays ctx after out_proj done)
//   [76800,79424)   misc: gl[64], wgt[64], red1[256], red2[256], mu[8], rv[8]
__global__ __launch_bounds__(NTHREADS, 2)
void fused_kernel(const float* __restrict__ feat,
                  const float* __restrict__ view_info,
                  const short* __restrict__ win_hi,
                  const short* __restrict__ win_lo,
                  const short* __restrict__ wout_b,
                  const short* __restrict__ wg1_b,
                  const float* __restrict__ b_in,
                  const float* __restrict__ b_out,
                  const float* __restrict__ b_g1,
                  const float* __restrict__ w2,
                  const float* __restrict__ b2,
                  const float* __restrict__ ln_g,
                  const float* __restrict__ ln_b,
                  float* __restrict__ out)
{
  extern __shared__ char smem[];
  float* qk  = (float*)smem;               // [64][132]
  short* att = (short*)smem;               // overlay: [64][264] bf16
  short* vv  = (short*)(smem + 33792);     // [64][72] bf16
  short* ctx = (short*)(smem + 43008);     // [64][264] bf16
  float* g1s = (float*)(smem + 43008);     // overlay: [64][65] fp32
  float* gl  = (float*)(smem + 76800);
  float* wgt = gl + 64;
  float* red1 = wgt + 64;
  float* red2 = red1 + 256;
  float* mus  = red2 + 256;
  float* rvs  = mus + 8;

  const int tid  = threadIdx.x;
  const int wv   = tid >> 6, lane = tid & 63;
  const int rg   = wv & 3, nhv = wv >> 2;    // row-group, n-half
  const int quad = lane >> 4, l15 = lane & 15;
  const int arow = rg*16 + l15;              // A-operand token row (0..63)
  const int crow0 = rg*16 + quad*4;          // C/D row base for this lane

  // ---- stage A (features + view_info) into registers, hi/lo bf16 split ----
  bf16x8 ahi[8], alo[8];
  {
    int n = arow & 7, lloc = arow >> 3;
    long l = (long)blockIdx.x * TL + lloc;
    const float* fb = feat + ((long)n * L_DIM + l) * C_DIM;
    const float* vb = view_info + n * C_DIM;
#pragma unroll
    for (int kc = 0; kc < 8; kc++){
      int k0 = kc*32 + quad*8;
      float4 x0 = *(const float4*)(fb + k0);
      float4 x1 = *(const float4*)(fb + k0 + 4);
      float4 v0 = *(const float4*)(vb + k0);
      float4 v1 = *(const float4*)(vb + k0 + 4);
      float xs[8] = {x0.x+v0.x, x0.y+v0.y, x0.z+v0.z, x0.w+v0.w,
                     x1.x+v1.x, x1.y+v1.y, x1.z+v1.z, x1.w+v1.w};
      bf16x8 h, lo;
#pragma unroll
      for (int j = 0; j < 8; j++){
        short hb = f2bf(xs[j]);
        h[j] = hb;
        lo[j] = f2bf(xs[j] - bf2f(hb));
      }
      ahi[kc] = h; alo[kc] = lo;
    }
  }

  // ================= per-head: qkv GEMM (3-term split) + attention =================
  for (int h = 0; h < NH; h++){
    if (h) __syncthreads();                 // prior attention done reading qk/v
#pragma unroll
    for (int p = 0; p < 3; p++){            // q, k, v
      const int rowbase = p*C_DIM + h*DH;
#pragma unroll
      for (int ntl = 0; ntl < 2; ntl++){
        int nt = nhv*2 + ntl;
        int colc = nt*16 + l15;             // 0..63 within chunk = W row
        const short* bhp = win_hi + (long)(rowbase + colc)*C_DIM + quad*8;
        const short* blp = win_lo + (long)(rowbase + colc)*C_DIM + quad*8;
        f32x4 acc = {0.f,0.f,0.f,0.f};
#pragma unroll
        for (int kc = 0; kc < 8; kc++){
          bf16x8 bh = *(const bf16x8*)(bhp + kc*32);
          bf16x8 bl = *(const bf16x8*)(blp + kc*32);
          acc = __builtin_amdgcn_mfma_f32_16x16x32_bf16(ahi[kc], bh, acc, 0,0,0);
          acc = __builtin_amdgcn_mfma_f32_16x16x32_bf16(ahi[kc], bl, acc, 0,0,0);
          acc = __builtin_amdgcn_mfma_f32_16x16x32_bf16(alo[kc], bh, acc, 0,0,0);
        }
        float bias = b_in[rowbase + colc];
        if (p < 2){
#pragma unroll
          for (int r = 0; r < 4; r++)
            qk[(crow0 + r)*QKPAD + p*64 + colc] = acc[r] + bias;
        } else {
#pragma unroll
          for (int r = 0; r < 4; r++)
            vv[(crow0 + r)*VPAD + colc] = f2bf(acc[r] + bias);
        }
      }
    }
    __syncthreads();                        // q,k,v complete for this head
    // ---- fp32 attention for head h: wave wv handles l_loc = wv, lane = nn*8+mm ----
    {
      int l2 = wv;
      int nn = lane >> 3, mm = lane & 7;
      int tq = l2*8 + nn;
      const float* qrow = qk + tq*QKPAD;                 // broadcast over mm
      const float* krow = qk + (l2*8 + mm)*QKPAD + 64;
      float s = 0.f;
#pragma unroll
      for (int d4 = 0; d4 < 16; d4++){
        float4 q4 = *(const float4*)(qrow + d4*4);
        float4 k4 = *(const float4*)(krow + d4*4);
        s += q4.x*k4.x + q4.y*k4.y + q4.z*k4.z + q4.w*k4.w;
      }
      s *= 0.125f;                          // 1/sqrt(64)
      float mx = s;
#pragma unroll
      for (int o = 1; o < 8; o <<= 1) mx = fmaxf(mx, __shfl_xor(mx, o));
      float e = __expf(s - mx);
      float sum = e;
#pragma unroll
      for (int o = 1; o < 8; o <<= 1) sum += __shfl_xor(sum, o);
      float attnw = e / sum;
      // ctx: this thread owns d-slice [mm*8, mm*8+8) of token tq
      float c8[8] = {0,0,0,0,0,0,0,0};
#pragma unroll
      for (int mp = 0; mp < 8; mp++){
        float aw = __shfl(attnw, (nn<<3) | mp);
        bf16x8 v8 = *(const bf16x8*)(vv + (l2*8 + mp)*VPAD + mm*8);
#pragma unroll
        for (int j = 0; j < 8; j++) c8[j] += aw * bf2f(v8[j]);
      }
      bf16x8 cp;
#pragma unroll
      for (int j = 0; j < 8; j++) cp[j] = f2bf(c8[j]);
      *(bf16x8*)(ctx + tq*WPAD + h*DH + mm*8) = cp;
    }
  }
  __syncthreads();  // ctx complete; qk region dead -> att may be written

  // ================= attended = ctx @ W_out^T + b_out (bf16 MFMA) =================
  {
    bf16x8 af[8];
#pragma unroll
    for (int kc = 0; kc < 8; kc++)
      af[kc] = *(const bf16x8*)(ctx + arow*WPAD + quad*8 + kc*32);
#pragma unroll
    for (int cc = 0; cc < 4; cc++){
#pragma unroll
      for (int ntl = 0; ntl < 2; ntl++){
        int nt = nhv*2 + ntl;
        int col = cc*64 + nt*16 + l15;
        const short* bp = wout_b + (long)col*C_DIM + quad*8;
        f32x4 acc = {0.f,0.f,0.f,0.f};
#pragma unroll
        for (int kc = 0; kc < 8; kc++){
          bf16x8 b = *(const bf16x8*)(bp + kc*32);
          acc = __builtin_amdgcn_mfma_f32_16x16x32_bf16(af[kc], b, acc, 0,0,0);
        }
        float bias = b_out[col];
#pragma unroll
        for (int r = 0; r < 4; r++)
          att[(crow0 + r)*WPAD + col] = f2bf(acc[r] + bias);
      }
    }
  }
  __syncthreads();  // att ready; ctx reads done -> g1s may be written

  // ================= gate hidden: g1 = relu(att @ Wg1^T + b) =================
  {
    bf16x8 gf[8];
#pragma unroll
    for (int kc = 0; kc < 8; kc++)
      gf[kc] = *(const bf16x8*)(att + arow*WPAD + quad*8 + kc*32);
#pragma unroll
    for (int ntl = 0; ntl < 2; ntl++){
      int nt = nhv*2 + ntl;
      int col = nt*16 + l15;                // 0..63
      const short* bp = wg1_b + (long)col*C_DIM + quad*8;
      f32x4 acc = {0.f,0.f,0.f,0.f};
#pragma unroll
      for (int kc = 0; kc < 8; kc++){
        bf16x8 b = *(const bf16x8*)(bp + kc*32);
        acc = __builtin_amdgcn_mfma_f32_16x16x32_bf16(gf[kc], b, acc, 0,0,0);
      }
      float bias = b_g1[col];
#pragma unroll
      for (int r = 0; r < 4; r++)
        g1s[(crow0 + r)*GPAD + col] = fmaxf(acc[r] + bias, 0.f);
    }
  }
  __syncthreads();

  // ---- gate scalar + sigmoid (4 threads per token) ----
  if (tid < 256){
    int t = tid >> 2, part = tid & 3;
    const float* g1r = g1s + t*GPAD + part*16;
    const float* w2p = w2 + part*16;
    float s = 0.f;
#pragma unroll
    for (int j = 0; j < 16; j++) s += g1r[j] * w2p[j];
    s += __shfl_xor(s, 1);
    s += __shfl_xor(s, 2);
    if (part == 0) gl[t] = 1.f / (1.f + __expf(-(s + b2[0])));
  }
  __syncthreads();
  // ---- softmax over views ----
  if (tid < 8){
    float v[8]; float mx = -1e30f;
    for (int n = 0; n < 8; n++){ v[n] = gl[tid*8+n]; mx = fmaxf(mx, v[n]); }
    float sum = 0.f;
    for (int n = 0; n < 8; n++){ v[n] = __expf(v[n]-mx); sum += v[n]; }
    float inv = 1.f/sum;
    for (int n = 0; n < 8; n++) wgt[tid*8+n] = v[n]*inv;
  }
  __syncthreads();

  // ---- fused = sum_n w_n * attended, then LayerNorm over C ----
  float f8[8];
  const int lfl = tid >> 5, ccf = tid & 31;
  if (tid < 256){
    float wloc[8];
#pragma unroll
    for (int n = 0; n < 8; n++) wloc[n] = wgt[lfl*8+n];
#pragma unroll
    for (int j = 0; j < 8; j++) f8[j] = 0.f;
#pragma unroll
    for (int n = 0; n < 8; n++){
      const short* ar = att + (lfl*8+n)*WPAD + ccf*8;
      bf16x8 a8 = *(const bf16x8*)ar;
      float aw = wloc[n];
#pragma unroll
      for (int j = 0; j < 8; j++) f8[j] += aw * bf2f(a8[j]);
    }
    float s = 0.f, s2 = 0.f;
#pragma unroll
    for (int j = 0; j < 8; j++){ s += f8[j]; s2 += f8[j]*f8[j]; }
    red1[lfl*32 + ccf] = s;
    red2[lfl*32 + ccf] = s2;
  }
  __syncthreads();
  if (tid < 8){
    float s = 0.f, s2 = 0.f;
    for (int i = 0; i < 32; i++){ s += red1[tid*32+i]; s2 += red2[tid*32+i]; }
    float mu = s * (1.f/256.f);
    float var = s2 * (1.f/256.f) - mu*mu;
    mus[tid] = mu;
    rvs[tid] = rsqrtf(var + 1e-5f);
  }
  __syncthreads();
  if (tid < 256){
    float mu = mus[lfl], rv = rvs[lfl];
    long lg = (long)blockIdx.x * TL + lfl;
    float* op = out + lg * C_DIM + ccf*8;
    float o8[8];
#pragma unroll
    for (int j = 0; j < 8; j++){
      int c = ccf*8 + j;
      o8[j] = (f8[j]-mu)*rv*ln_g[c] + ln_b[c];
    }
    *(float4*)(op)   = make_float4(o8[0],o8[1],o8[2],o8[3]);
    *(float4*)(op+4) = make_float4(o8[4],o8[5],o8[6],o8[7]);
  }
}

extern "C" void kernel_launch(void* const* d_in, const int* in_sizes, int n_in,
                              void* d_out, int out_size, void* d_ws, size_t ws_size,
                              hipStream_t stream){
  const float* feat  = (const float*)d_in[0];
  const float* vw    = (const float*)d_in[1];
  const float* vb    = (const float*)d_in[2];
  const float* w_in  = (const float*)d_in[3];
  const float* b_in  = (const float*)d_in[4];
  const float* w_out = (const float*)d_in[5];
  const float* b_out = (const float*)d_in[6];
  const float* w_g1  = (const float*)d_in[7];
  const float* b_g1  = (const float*)d_in[8];
  const float* w2    = (const float*)d_in[9];
  const float* b2    = (const float*)d_in[10];
  const float* lng   = (const float*)d_in[11];
  const float* lnb   = (const float*)d_in[12];

  char* ws = (char*)d_ws;
  float* view_info = (float*)ws;              //   8192 B
  short* win_hi = (short*)(ws + 8192);        // 393216 B
  short* win_lo = (short*)(ws + 401408);      // 393216 B
  short* wout_b = (short*)(ws + 794624);      // 131072 B
  short* wg1_b  = (short*)(ws + 925696);      //  32768 B   (total 958464 B)

  prep_kernel<<<64, 256, 0, stream>>>(vw, vb, w_in, w_out, w_g1,
                                      view_info, win_hi, win_lo, wout_b, wg1_b);
  fused_kernel<<<L_DIM/TL, NTHREADS, 79424, stream>>>(
      feat, view_info, win_hi, win_lo, wout_b, wg1_b,
      b_in, b_out, b_g1, w2, b2, lng, lnb, (float*)d_out);
}

// Round 5
// 828.836 us; speedup vs baseline: 1.3967x; 1.3967x over previous
//
#include <hip/hip_runtime.h>
#include <hip/hip_bf16.h>

#define L_DIM 16384
#define C_DIM 256
#define NV 8
#define NH 4
#define DH 64
#define TL 8          // l's per block
#define NTHREADS 512  // 8 waves

// LDS strides
#define QKPADS 132    // bf16 shorts per row for q|k (66 words % 32 = 2)
#define VPADS 68      // bf16 shorts per row for v   (34 words % 32 = 2)
#define GPAD 65       // fp32 per row for g1s        (65 % 32 = 1)
// ctx/att: 64 rows x 256 bf16, XOR-swizzled 16B slots (slot' = slot ^ (row&31)),
// row stride 256 shorts (128 words). Fragment reads land 2 lanes/bank = free.

typedef __attribute__((ext_vector_type(8))) short bf16x8;
typedef __attribute__((ext_vector_type(4))) float f32x4;

__device__ inline float bf2f(short s){
  union { unsigned u; float f; } v; v.u = ((unsigned)(unsigned short)s) << 16; return v.f;
}
__device__ inline short f2bf(float f){
  __hip_bfloat16 h = __float2bfloat16(f);
  union { __hip_bfloat16 h; short s; } v; v.h = h; return v.s;
}

// ---------------- prep: view_info + pack weights into MFMA fragment order ----
// Packed layout: frag index ((chunk*4 + nt)*8 + kc)*64 + lane, 8 bf16 each.
// Element j of that frag = W[chunkrow + nt*16 + (lane&15)][(lane>>4)*8 + kc*32 + j].
// A wave reading one (nt,kc) line = 64 lanes x 16B contiguous -> fully coalesced.
__global__ void prep_kernel(const float* __restrict__ vw, const float* __restrict__ vb,
                            const float* __restrict__ w_in, const float* __restrict__ w_out,
                            const float* __restrict__ w_g1,
                            float* __restrict__ view_info, short* __restrict__ win_hi,
                            short* __restrict__ win_lo, short* __restrict__ wout_pk,
                            short* __restrict__ wg1_pk){
  int tid = threadIdx.x, bid = blockIdx.x;
  if (bid == 0){
    int c = tid;                       // 256 threads, one channel each
    float rs = 0.f;
    for (int k = 0; k < C_DIM; k++) rs += vw[c*C_DIM + k];
    float b = vb[c];
    for (int n = 0; n < NV; n++) view_info[n*C_DIM + c] = (n * 0.125f) * rs + b;
  }
  int gid = bid * blockDim.x + tid;
  int stride = gridDim.x * blockDim.x;
  // frag counts: win 12 chunks(h*3+p) *4nt*8kc*64 = 24576 ; wout 4*4*8*64 = 8192 ; wg1 4*8*64*... = 2048
  const int NWIN = 24576, NWOUT = 8192, NWG = 2048;
  for (int f = gid; f < NWIN + NWOUT + NWG; f += stride){
    if (f < NWIN){
      int lane = f & 63, kc = (f>>6)&7, nt = (f>>9)&3, pc = f>>11;   // pc = h*3+p
      int p = pc % 3, h = pc / 3;
      int row = p*C_DIM + h*DH + nt*16 + (lane&15);
      int col = (lane>>4)*8 + kc*32;
      const float* src = w_in + (long)row*C_DIM + col;
      short* dh = win_hi + (long)f*8;
      short* dl = win_lo + (long)f*8;
#pragma unroll
      for (int j = 0; j < 8; j++){
        float v = src[j]; short hi = f2bf(v);
        dh[j] = hi; dl[j] = f2bf(v - bf2f(hi));
      }
    } else if (f < NWIN + NWOUT){
      int f2 = f - NWIN;
      int lane = f2 & 63, kc = (f2>>6)&7, nt = (f2>>9)&3, cc = f2>>11;
      int row = cc*64 + nt*16 + (lane&15);
      int col = (lane>>4)*8 + kc*32;
      const float* src = w_out + (long)row*C_DIM + col;
      short* d = wout_pk + (long)f2*8;
#pragma unroll
      for (int j = 0; j < 8; j++) d[j] = f2bf(src[j]);
    } else {
      int f3 = f - NWIN - NWOUT;
      int lane = f3 & 63, kc = (f3>>6)&7, nt = (f3>>9)&3;
      int row = nt*16 + (lane&15);
      int col = (lane>>4)*8 + kc*32;
      const float* src = w_g1 + (long)row*C_DIM + col;
      short* d = wg1_pk + (long)f3*8;
#pragma unroll
      for (int j = 0; j < 8; j++) d[j] = f2bf(src[j]);
    }
  }
}

// ---------------- fused main kernel: one block = 8 l's (64 tokens) ----------------
// B-fragments come straight from the PACKED global arrays (coalesced 1KB wave
// lines, L1-shared across waves) -> no W in LDS, no staging barriers.
// LDS carve (dynamic, 68160 B -> 2 blocks/CU):
//   region A [0,32768):
//     qk  bf16 [64][QKPADS]  (q cols 0-63, k 64-127, per head)   [0,16896)
//     v   bf16 [64][VPADS]                                        [16896,25600)
//     att bf16 [64][256] XOR-swizzled  (overlays qk+v after heads done)
//   [32768,65536)  ctx bf16 [64][256] XOR-swizzled
//                  g1s fp32 [64][GPAD] (overlays ctx after out_proj)
//   [65536,68160)  misc: gl[64], wgt[64], red1[256], red2[256], mu[8], rv[8]
__global__ __launch_bounds__(NTHREADS, 2)
void fused_kernel(const float* __restrict__ feat,
                  const float* __restrict__ view_info,
                  const short* __restrict__ win_hi,
                  const short* __restrict__ win_lo,
                  const short* __restrict__ wout_pk,
                  const short* __restrict__ wg1_pk,
                  const float* __restrict__ b_in,
                  const float* __restrict__ b_out,
                  const float* __restrict__ b_g1,
                  const float* __restrict__ w2,
                  const float* __restrict__ b2,
                  const float* __restrict__ ln_g,
                  const float* __restrict__ ln_b,
                  float* __restrict__ out)
{
  extern __shared__ char smem[];
  short* qk  = (short*)smem;               // [64][132] bf16
  short* vv  = (short*)(smem + 16896);     // [64][68] bf16
  short* att = (short*)smem;               // overlay: [64][256] bf16 swizzled
  short* ctx = (short*)(smem + 32768);     // [64][256] bf16 swizzled
  float* g1s = (float*)(smem + 32768);     // overlay: [64][65] fp32
  float* gl  = (float*)(smem + 65536);
  float* wgt = gl + 64;
  float* red1 = wgt + 64;
  float* red2 = red1 + 256;
  float* mus  = red2 + 256;
  float* rvs  = mus + 8;

  const int tid  = threadIdx.x;
  const int wv   = tid >> 6, lane = tid & 63;
  const int rg   = wv & 3, nhv = wv >> 2;    // row-group, n-half
  const int quad = lane >> 4, l15 = lane & 15;
  const int arow = rg*16 + l15;              // A-operand token row (0..63)
  const int crow0 = rg*16 + quad*4;          // C/D row base for this lane

  // ---- stage A (features + view_info) into registers, hi/lo bf16 split ----
  bf16x8 ahi[8], alo[8];
  {
    int n = arow & 7, lloc = arow >> 3;
    long l = (long)blockIdx.x * TL + lloc;
    const float* fb = feat + ((long)n * L_DIM + l) * C_DIM;
    const float* vb = view_info + n * C_DIM;
#pragma unroll
    for (int kc = 0; kc < 8; kc++){
      int k0 = kc*32 + quad*8;
      float4 x0 = *(const float4*)(fb + k0);
      float4 x1 = *(const float4*)(fb + k0 + 4);
      float4 v0 = *(const float4*)(vb + k0);
      float4 v1 = *(const float4*)(vb + k0 + 4);
      float xs[8] = {x0.x+v0.x, x0.y+v0.y, x0.z+v0.z, x0.w+v0.w,
                     x1.x+v1.x, x1.y+v1.y, x1.z+v1.z, x1.w+v1.w};
      bf16x8 h, lo;
#pragma unroll
      for (int j = 0; j < 8; j++){
        short hb = f2bf(xs[j]);
        h[j] = hb;
        lo[j] = f2bf(xs[j] - bf2f(hb));
      }
      ahi[kc] = h; alo[kc] = lo;
    }
  }

  // ================= per-head: qkv GEMM (3-term split) + attention =================
  for (int h = 0; h < NH; h++){
    if (h) __syncthreads();                 // prior attention done reading qk/v
#pragma unroll
    for (int p = 0; p < 3; p++){            // q, k, v
      const int rowbase = p*C_DIM + h*DH;
#pragma unroll
      for (int ntl = 0; ntl < 2; ntl++){
        int nt = nhv*2 + ntl;
        // packed fragment line base for (h,p,nt): coalesced 1KB wave reads
        const short* ph = win_hi + (long)(((h*3 + p)*4 + nt)*8)*512 + lane*8;
        const short* pl = win_lo + (long)(((h*3 + p)*4 + nt)*8)*512 + lane*8;
        f32x4 acc = {0.f,0.f,0.f,0.f};
#pragma unroll
        for (int kc = 0; kc < 8; kc++){
          bf16x8 bh = *(const bf16x8*)(ph + kc*512);
          bf16x8 bl = *(const bf16x8*)(pl + kc*512);
          acc = __builtin_amdgcn_mfma_f32_16x16x32_bf16(ahi[kc], bh, acc, 0,0,0);
          acc = __builtin_amdgcn_mfma_f32_16x16x32_bf16(ahi[kc], bl, acc, 0,0,0);
          acc = __builtin_amdgcn_mfma_f32_16x16x32_bf16(alo[kc], bh, acc, 0,0,0);
        }
        int colc = nt*16 + l15;             // 0..63 within chunk
        float bias = b_in[rowbase + colc];
        if (p < 2){
#pragma unroll
          for (int r = 0; r < 4; r++)
            qk[(crow0 + r)*QKPADS + p*64 + colc] = f2bf(acc[r] + bias);
        } else {
#pragma unroll
          for (int r = 0; r < 4; r++)
            vv[(crow0 + r)*VPADS + colc] = f2bf(acc[r] + bias);
        }
      }
    }
    __syncthreads();                        // q,k,v complete for this head
    // ---- attention for head h: wave wv handles l_loc = wv, lane = nn*8+mm ----
    {
      int l2 = wv;
      int nn = lane >> 3, mm = lane & 7;
      int tq = l2*8 + nn;
      const short* qrow = qk + tq*QKPADS;              // broadcast over mm
      const short* krow = qk + (l2*8 + mm)*QKPADS + 64;
      float s = 0.f;
#pragma unroll
      for (int d8 = 0; d8 < 8; d8++){
        bf16x8 q8 = *(const bf16x8*)(qrow + d8*8);
        bf16x8 k8 = *(const bf16x8*)(krow + d8*8);
#pragma unroll
        for (int j = 0; j < 8; j++) s += bf2f(q8[j]) * bf2f(k8[j]);
      }
      s *= 0.125f;                          // 1/sqrt(64)
      float mx = s;
#pragma unroll
      for (int o = 1; o < 8; o <<= 1) mx = fmaxf(mx, __shfl_xor(mx, o));
      float e = __expf(s - mx);
      float sum = e;
#pragma unroll
      for (int o = 1; o < 8; o <<= 1) sum += __shfl_xor(sum, o);
      float attnw = e / sum;
      // ctx: this thread owns d-slice [mm*8, mm*8+8) of token tq
      float c8[8] = {0,0,0,0,0,0,0,0};
#pragma unroll
      for (int mp = 0; mp < 8; mp++){
        float aw = __shfl(attnw, (nn<<3) | mp);
        bf16x8 v8 = *(const bf16x8*)(vv + (l2*8 + mp)*VPADS + mm*8);
#pragma unroll
        for (int j = 0; j < 8; j++) c8[j] += aw * bf2f(v8[j]);
      }
      bf16x8 cp;
#pragma unroll
      for (int j = 0; j < 8; j++) cp[j] = f2bf(c8[j]);
      int slot = h*8 + mm;                  // 16B slot, XOR-swizzled
      *(bf16x8*)(ctx + tq*256 + ((slot ^ (tq & 31)))*8) = cp;
    }
  }
  __syncthreads();  // ctx complete; qk/v dead -> att may be written

  // ================= attended = ctx @ W_out^T + b_out (bf16 MFMA) =================
  {
    bf16x8 af[8];
#pragma unroll
    for (int kc = 0; kc < 8; kc++)
      af[kc] = *(const bf16x8*)(ctx + arow*256 + ((quad + 4*kc) ^ (arow & 31))*8);
#pragma unroll
    for (int cc = 0; cc < 4; cc++){
#pragma unroll
      for (int ntl = 0; ntl < 2; ntl++){
        int nt = nhv*2 + ntl;
        const short* bp = wout_pk + (long)((cc*4 + nt)*8)*512 + lane*8;
        f32x4 acc = {0.f,0.f,0.f,0.f};
#pragma unroll
        for (int kc = 0; kc < 8; kc++){
          bf16x8 b = *(const bf16x8*)(bp + kc*512);
          acc = __builtin_amdgcn_mfma_f32_16x16x32_bf16(af[kc], b, acc, 0,0,0);
        }
        int col = cc*64 + nt*16 + l15;
        float bias = b_out[col];
        int slot = col >> 3, j = col & 7;
#pragma unroll
        for (int r = 0; r < 4; r++){
          int row = crow0 + r;
          att[row*256 + (slot ^ (row & 31))*8 + j] = f2bf(acc[r] + bias);
        }
      }
    }
  }
  __syncthreads();  // att ready; ctx dead -> g1s may be written

  // ================= gate hidden: g1 = relu(att @ Wg1^T + b) =================
  {
    bf16x8 gf[8];
#pragma unroll
    for (int kc = 0; kc < 8; kc++)
      gf[kc] = *(const bf16x8*)(att + arow*256 + ((quad + 4*kc) ^ (arow & 31))*8);
#pragma unroll
    for (int ntl = 0; ntl < 2; ntl++){
      int nt = nhv*2 + ntl;
      const short* bp = wg1_pk + (long)(nt*8)*512 + lane*8;
      f32x4 acc = {0.f,0.f,0.f,0.f};
#pragma unroll
      for (int kc = 0; kc < 8; kc++){
        bf16x8 b = *(const bf16x8*)(bp + kc*512);
        acc = __builtin_amdgcn_mfma_f32_16x16x32_bf16(gf[kc], b, acc, 0,0,0);
      }
      int col = nt*16 + l15;                // 0..63
      float bias = b_g1[col];
#pragma unroll
      for (int r = 0; r < 4; r++)
        g1s[(crow0 + r)*GPAD + col] = fmaxf(acc[r] + bias, 0.f);
    }
  }
  __syncthreads();

  // ---- gate scalar + sigmoid (4 threads per token) ----
  if (tid < 256){
    int t = tid >> 2, part = tid & 3;
    const float* g1r = g1s + t*GPAD + part*16;
    const float* w2p = w2 + part*16;
    float s = 0.f;
#pragma unroll
    for (int j = 0; j < 16; j++) s += g1r[j] * w2p[j];
    s += __shfl_xor(s, 1);
    s += __shfl_xor(s, 2);
    if (part == 0) gl[t] = 1.f / (1.f + __expf(-(s + b2[0])));
  }
  __syncthreads();
  // ---- softmax over views ----
  if (tid < 8){
    float v[8]; float mx = -1e30f;
    for (int n = 0; n < 8; n++){ v[n] = gl[tid*8+n]; mx = fmaxf(mx, v[n]); }
    float sum = 0.f;
    for (int n = 0; n < 8; n++){ v[n] = __expf(v[n]-mx); sum += v[n]; }
    float inv = 1.f/sum;
    for (int n = 0; n < 8; n++) wgt[tid*8+n] = v[n]*inv;
  }
  __syncthreads();

  // ---- fused = sum_n w_n * attended, then LayerNorm over C ----
  float f8[8];
  const int lfl = tid >> 5, ccf = tid & 31;
  if (tid < 256){
    float wloc[8];
#pragma unroll
    for (int n = 0; n < 8; n++) wloc[n] = wgt[lfl*8+n];
#pragma unroll
    for (int j = 0; j < 8; j++) f8[j] = 0.f;
#pragma unroll
    for (int n = 0; n < 8; n++){
      int row = lfl*8 + n;
      bf16x8 a8 = *(const bf16x8*)(att + row*256 + ((ccf ^ (row & 31)))*8);
      float aw = wloc[n];
#pragma unroll
      for (int j = 0; j < 8; j++) f8[j] += aw * bf2f(a8[j]);
    }
    float s = 0.f, s2 = 0.f;
#pragma unroll
    for (int j = 0; j < 8; j++){ s += f8[j]; s2 += f8[j]*f8[j]; }
    red1[lfl*32 + ccf] = s;
    red2[lfl*32 + ccf] = s2;
  }
  __syncthreads();
  if (tid < 8){
    float s = 0.f, s2 = 0.f;
    for (int i = 0; i < 32; i++){ s += red1[tid*32+i]; s2 += red2[tid*32+i]; }
    float mu = s * (1.f/256.f);
    float var = s2 * (1.f/256.f) - mu*mu;
    mus[tid] = mu;
    rvs[tid] = rsqrtf(var + 1e-5f);
  }
  __syncthreads();
  if (tid < 256){
    float mu = mus[lfl], rv = rvs[lfl];
    long lg = (long)blockIdx.x * TL + lfl;
    float* op = out + lg * C_DIM + ccf*8;
    float o8[8];
#pragma unroll
    for (int j = 0; j < 8; j++){
      int c = ccf*8 + j;
      o8[j] = (f8[j]-mu)*rv*ln_g[c] + ln_b[c];
    }
    *(float4*)(op)   = make_float4(o8[0],o8[1],o8[2],o8[3]);
    *(float4*)(op+4) = make_float4(o8[4],o8[5],o8[6],o8[7]);
  }
}

extern "C" void kernel_launch(void* const* d_in, const int* in_sizes, int n_in,
                              void* d_out, int out_size, void* d_ws, size_t ws_size,
                              hipStream_t stream){
  const float* feat  = (const float*)d_in[0];
  const float* vw    = (const float*)d_in[1];
  const float* vb    = (const float*)d_in[2];
  const float* w_in  = (const float*)d_in[3];
  const float* b_in  = (const float*)d_in[4];
  const float* w_out = (const float*)d_in[5];
  const float* b_out = (const float*)d_in[6];
  const float* w_g1  = (const float*)d_in[7];
  const float* b_g1  = (const float*)d_in[8];
  const float* w2    = (const float*)d_in[9];
  const float* b2    = (const float*)d_in[10];
  const float* lng   = (const float*)d_in[11];
  const float* lnb   = (const float*)d_in[12];

  char* ws = (char*)d_ws;
  float* view_info = (float*)ws;              //   8192 B
  short* win_hi  = (short*)(ws + 8192);       // 393216 B (packed)
  short* win_lo  = (short*)(ws + 401408);     // 393216 B (packed)
  short* wout_pk = (short*)(ws + 794624);     // 131072 B (packed)
  short* wg1_pk  = (short*)(ws + 925696);     //  32768 B (packed)  total 958464 B

  prep_kernel<<<64, 256, 0, stream>>>(vw, vb, w_in, w_out, w_g1,
                                      view_info, win_hi, win_lo, wout_pk, wg1_pk);
  fused_kernel<<<L_DIM/TL, NTHREADS, 68160, stream>>>(
      feat, view_info, win_hi, win_lo, wout_pk, wg1_pk,
      b_in, b_out, b_g1, w2, b2, lng, lnb, (float*)d_out);
}

// Round 6
// 629.247 us; speedup vs baseline: 1.8397x; 1.3172x over previous
//
#include <hip/hip_runtime.h>
#include <hip/hip_bf16.h>

#define L_DIM 16384
#define C_DIM 256
#define NV 8
#define NH 4
#define DH 64
#define TL 4          // l's per block (32 token rows)
#define NTHREADS 256  // 4 waves

// LDS strides
#define QKPADS 132    // bf16 shorts per row for q|k (66 words % 32 = 2)
#define VPADS 68      // bf16 shorts per row for v   (34 words % 32 = 2)
#define GPAD 65       // fp32 per row for g1s        (65 % 32 = 1)
// ctx/att: 32 rows x 256 bf16, XOR-swizzled 16B slots (slot' = slot ^ (row&31))

typedef __attribute__((ext_vector_type(8))) short bf16x8;
typedef __attribute__((ext_vector_type(4))) float f32x4;

__device__ inline float bf2f(short s){
  union { unsigned u; float f; } v; v.u = ((unsigned)(unsigned short)s) << 16; return v.f;
}
__device__ inline short f2bf(float f){
  __hip_bfloat16 h = __float2bfloat16(f);
  union { __hip_bfloat16 h; short s; } v; v.h = h; return v.s;
}

// ---------------- prep: view_info + pack weights into MFMA fragment order ----
// Packed layout: frag index ((chunk*4 + nt)*8 + kc)*64 + lane, 8 bf16 each.
// Element j = W[chunkrow + nt*16 + (lane&15)][(lane>>4)*8 + kc*32 + j].
// A wave reading one (nt,kc) line = 64 lanes x 16B contiguous -> fully coalesced.
__global__ void prep_kernel(const float* __restrict__ vw, const float* __restrict__ vb,
                            const float* __restrict__ w_in, const float* __restrict__ w_out,
                            const float* __restrict__ w_g1,
                            float* __restrict__ view_info, short* __restrict__ win_hi,
                            short* __restrict__ win_lo, short* __restrict__ wout_pk,
                            short* __restrict__ wg1_pk){
  int tid = threadIdx.x, bid = blockIdx.x;
  if (bid == 0){
    int c = tid;                       // 256 threads, one channel each
    float rs = 0.f;
    for (int k = 0; k < C_DIM; k++) rs += vw[c*C_DIM + k];
    float b = vb[c];
    for (int n = 0; n < NV; n++) view_info[n*C_DIM + c] = (n * 0.125f) * rs + b;
  }
  int gid = bid * blockDim.x + tid;
  int stride = gridDim.x * blockDim.x;
  const int NWIN = 24576, NWOUT = 8192, NWG = 2048;
  for (int f = gid; f < NWIN + NWOUT + NWG; f += stride){
    if (f < NWIN){
      int lane = f & 63, kc = (f>>6)&7, nt = (f>>9)&3, pc = f>>11;   // pc = h*3+p
      int p = pc % 3, h = pc / 3;
      int row = p*C_DIM + h*DH + nt*16 + (lane&15);
      int col = (lane>>4)*8 + kc*32;
      const float* src = w_in + (long)row*C_DIM + col;
      short* dh = win_hi + (long)f*8;
      short* dl = win_lo + (long)f*8;
#pragma unroll
      for (int j = 0; j < 8; j++){
        float v = src[j]; short hi = f2bf(v);
        dh[j] = hi; dl[j] = f2bf(v - bf2f(hi));
      }
    } else if (f < NWIN + NWOUT){
      int f2 = f - NWIN;
      int lane = f2 & 63, kc = (f2>>6)&7, nt = (f2>>9)&3, cc = f2>>11;
      int row = cc*64 + nt*16 + (lane&15);
      int col = (lane>>4)*8 + kc*32;
      const float* src = w_out + (long)row*C_DIM + col;
      short* d = wout_pk + (long)f2*8;
#pragma unroll
      for (int j = 0; j < 8; j++) d[j] = f2bf(src[j]);
    } else {
      int f3 = f - NWIN - NWOUT;
      int lane = f3 & 63, kc = (f3>>6)&7, nt = (f3>>9)&3;
      int row = nt*16 + (lane&15);
      int col = (lane>>4)*8 + kc*32;
      const float* src = w_g1 + (long)row*C_DIM + col;
      short* d = wg1_pk + (long)f3*8;
#pragma unroll
      for (int j = 0; j < 8; j++) d[j] = f2bf(src[j]);
    }
  }
}

// ---------------- fused main kernel: one block = 4 l's (32 tokens), 4 waves ----
// Wave w owns BOTH 16-row tiles (2-rt register blocking: each B-frag -> 2 MFMAs)
// and col-tile nt=w. qkv = 2-term (A plain bf16 x (Whi + Wlo)).
// LDS carve (dynamic, 34080 B -> 4 blocks/CU):
//   [0,16384)      qk [32][132]b + vv [32][68]b at +8448; att [32][256]b swz overlay
//   [16384,32768)  ctx [32][256]b swz; g1s [32][65]f overlay
//   [32768,34080)  misc: gl[32], wgt[32], red1[128], red2[128], mus[4], rvs[4]
__global__ __launch_bounds__(NTHREADS, 4)
void fused_kernel(const float* __restrict__ feat,
                  const float* __restrict__ view_info,
                  const short* __restrict__ win_hi,
                  const short* __restrict__ win_lo,
                  const short* __restrict__ wout_pk,
                  const short* __restrict__ wg1_pk,
                  const float* __restrict__ b_in,
                  const float* __restrict__ b_out,
                  const float* __restrict__ b_g1,
                  const float* __restrict__ w2,
                  const float* __restrict__ b2,
                  const float* __restrict__ ln_g,
                  const float* __restrict__ ln_b,
                  float* __restrict__ out)
{
  extern __shared__ char smem[];
  short* qk  = (short*)smem;               // [32][132] bf16
  short* vv  = (short*)(smem + 8448);      // [32][68] bf16
  short* att = (short*)smem;               // overlay: [32][256] bf16 swizzled
  short* ctx = (short*)(smem + 16384);     // [32][256] bf16 swizzled
  float* g1s = (float*)(smem + 16384);     // overlay: [32][65] fp32
  float* gl  = (float*)(smem + 32768);     // [32]
  float* wgt = gl + 32;                    // [32]
  float* red1 = wgt + 32;                  // [128]
  float* red2 = red1 + 128;                // [128]
  float* mus  = red2 + 128;                // [4]
  float* rvs  = mus + 4;                   // [4]

  const int tid  = threadIdx.x;
  const int wv   = tid >> 6, lane = tid & 63;
  const int quad = lane >> 4, l15 = lane & 15;

  // ---- stage A (features + view_info) into registers, plain bf16, 2 row-tiles ----
  bf16x8 ahi[2][8];
#pragma unroll
  for (int tt = 0; tt < 2; tt++){
    int row = tt*16 + l15;
    int n = row & 7, lloc = row >> 3;
    long l = (long)blockIdx.x * TL + lloc;
    const float* fb = feat + ((long)n * L_DIM + l) * C_DIM;
    const float* vb = view_info + n * C_DIM;
#pragma unroll
    for (int kc = 0; kc < 8; kc++){
      int k0 = kc*32 + quad*8;
      float4 x0 = *(const float4*)(fb + k0);
      float4 x1 = *(const float4*)(fb + k0 + 4);
      float4 v0 = *(const float4*)(vb + k0);
      float4 v1 = *(const float4*)(vb + k0 + 4);
      bf16x8 hfr;
      hfr[0] = f2bf(x0.x+v0.x); hfr[1] = f2bf(x0.y+v0.y);
      hfr[2] = f2bf(x0.z+v0.z); hfr[3] = f2bf(x0.w+v0.w);
      hfr[4] = f2bf(x1.x+v1.x); hfr[5] = f2bf(x1.y+v1.y);
      hfr[6] = f2bf(x1.z+v1.z); hfr[7] = f2bf(x1.w+v1.w);
      ahi[tt][kc] = hfr;
    }
  }

  // ================= per-head: qkv GEMM (2-term) + attention =================
  for (int h = 0; h < NH; h++){
    if (h) __syncthreads();                 // prior attention done reading qk/vv
#pragma unroll
    for (int p = 0; p < 3; p++){            // q, k, v
      const int rowbase = p*C_DIM + h*DH;
      const short* ph = win_hi + (long)(((h*3 + p)*4 + wv)*8)*512 + lane*8;
      const short* pl = win_lo + (long)(((h*3 + p)*4 + wv)*8)*512 + lane*8;
      f32x4 acc0 = {0.f,0.f,0.f,0.f}, acc1 = {0.f,0.f,0.f,0.f};
#pragma unroll
      for (int kc = 0; kc < 8; kc++){
        bf16x8 bh = *(const bf16x8*)(ph + kc*512);
        bf16x8 bl = *(const bf16x8*)(pl + kc*512);
        acc0 = __builtin_amdgcn_mfma_f32_16x16x32_bf16(ahi[0][kc], bh, acc0, 0,0,0);
        acc0 = __builtin_amdgcn_mfma_f32_16x16x32_bf16(ahi[0][kc], bl, acc0, 0,0,0);
        acc1 = __builtin_amdgcn_mfma_f32_16x16x32_bf16(ahi[1][kc], bh, acc1, 0,0,0);
        acc1 = __builtin_amdgcn_mfma_f32_16x16x32_bf16(ahi[1][kc], bl, acc1, 0,0,0);
      }
      int colc = wv*16 + l15;               // 0..63 within chunk
      float bias = b_in[rowbase + colc];
      if (p < 2){
#pragma unroll
        for (int r = 0; r < 4; r++){
          qk[(quad*4 + r)*QKPADS + p*64 + colc]      = f2bf(acc0[r] + bias);
          qk[(16 + quad*4 + r)*QKPADS + p*64 + colc] = f2bf(acc1[r] + bias);
        }
      } else {
#pragma unroll
        for (int r = 0; r < 4; r++){
          vv[(quad*4 + r)*VPADS + colc]      = f2bf(acc0[r] + bias);
          vv[(16 + quad*4 + r)*VPADS + colc] = f2bf(acc1[r] + bias);
        }
      }
    }
    __syncthreads();                        // q,k,v complete for this head
    // ---- attention for head h: wave wv handles l_loc = wv, lane = nn*8+mm ----
    {
      int l2 = wv;                          // 0..3
      int nn = lane >> 3, mm = lane & 7;
      int tq = l2*8 + nn;
      const short* qrow = qk + tq*QKPADS;              // broadcast over mm
      const short* krow = qk + (l2*8 + mm)*QKPADS + 64;
      float s = 0.f;
#pragma unroll
      for (int d8 = 0; d8 < 8; d8++){
        bf16x8 q8 = *(const bf16x8*)(qrow + d8*8);
        bf16x8 k8 = *(const bf16x8*)(krow + d8*8);
#pragma unroll
        for (int j = 0; j < 8; j++) s += bf2f(q8[j]) * bf2f(k8[j]);
      }
      s *= 0.125f;                          // 1/sqrt(64)
      float mx = s;
#pragma unroll
      for (int o = 1; o < 8; o <<= 1) mx = fmaxf(mx, __shfl_xor(mx, o));
      float e = __expf(s - mx);
      float sum = e;
#pragma unroll
      for (int o = 1; o < 8; o <<= 1) sum += __shfl_xor(sum, o);
      float attnw = e / sum;
      // ctx: this thread owns d-slice [mm*8, mm*8+8) of token tq
      float c8[8] = {0,0,0,0,0,0,0,0};
#pragma unroll
      for (int mp = 0; mp < 8; mp++){
        float aw = __shfl(attnw, (nn<<3) | mp);
        bf16x8 v8 = *(const bf16x8*)(vv + (l2*8 + mp)*VPADS + mm*8);
#pragma unroll
        for (int j = 0; j < 8; j++) c8[j] += aw * bf2f(v8[j]);
      }
      bf16x8 cp;
#pragma unroll
      for (int j = 0; j < 8; j++) cp[j] = f2bf(c8[j]);
      int slot = h*8 + mm;                  // 16B slot, XOR-swizzled
      *(bf16x8*)(ctx + tq*256 + ((slot ^ (tq & 31)))*8) = cp;
    }
  }
  __syncthreads();  // ctx complete; qk/vv dead -> att may be written

  // ================= attended = ctx @ W_out^T + b_out (bf16 MFMA) =================
  {
    bf16x8 af0[8], af1[8];
#pragma unroll
    for (int kc = 0; kc < 8; kc++){
      int r0 = l15, r1 = 16 + l15;
      af0[kc] = *(const bf16x8*)(ctx + r0*256 + ((quad + 4*kc) ^ (r0 & 31))*8);
      af1[kc] = *(const bf16x8*)(ctx + r1*256 + ((quad + 4*kc) ^ (r1 & 31))*8);
    }
#pragma unroll
    for (int nt = 0; nt < 4; nt++){
      const short* bp = wout_pk + (long)((wv*4 + nt)*8)*512 + lane*8;
      f32x4 acc0 = {0.f,0.f,0.f,0.f}, acc1 = {0.f,0.f,0.f,0.f};
#pragma unroll
      for (int kc = 0; kc < 8; kc++){
        bf16x8 b = *(const bf16x8*)(bp + kc*512);
        acc0 = __builtin_amdgcn_mfma_f32_16x16x32_bf16(af0[kc], b, acc0, 0,0,0);
        acc1 = __builtin_amdgcn_mfma_f32_16x16x32_bf16(af1[kc], b, acc1, 0,0,0);
      }
      int col = wv*64 + nt*16 + l15;
      float bias = b_out[col];
      int slot = col >> 3, j = col & 7;
#pragma unroll
      for (int r = 0; r < 4; r++){
        int row0 = quad*4 + r, row1 = 16 + quad*4 + r;
        att[row0*256 + ((slot ^ (row0 & 31)))*8 + j] = f2bf(acc0[r] + bias);
        att[row1*256 + ((slot ^ (row1 & 31)))*8 + j] = f2bf(acc1[r] + bias);
      }
    }
  }
  __syncthreads();  // att ready; ctx dead -> g1s may be written

  // ================= gate hidden: g1 = relu(att @ Wg1^T + b) =================
  {
    bf16x8 gf0[8], gf1[8];
#pragma unroll
    for (int kc = 0; kc < 8; kc++){
      int r0 = l15, r1 = 16 + l15;
      gf0[kc] = *(const bf16x8*)(att + r0*256 + ((quad + 4*kc) ^ (r0 & 31))*8);
      gf1[kc] = *(const bf16x8*)(att + r1*256 + ((quad + 4*kc) ^ (r1 & 31))*8);
    }
    const short* bp = wg1_pk + (long)(wv*8)*512 + lane*8;
    f32x4 acc0 = {0.f,0.f,0.f,0.f}, acc1 = {0.f,0.f,0.f,0.f};
#pragma unroll
    for (int kc = 0; kc < 8; kc++){
      bf16x8 b = *(const bf16x8*)(bp + kc*512);
      acc0 = __builtin_amdgcn_mfma_f32_16x16x32_bf16(gf0[kc], b, acc0, 0,0,0);
      acc1 = __builtin_amdgcn_mfma_f32_16x16x32_bf16(gf1[kc], b, acc1, 0,0,0);
    }
    int col = wv*16 + l15;                  // 0..63
    float bias = b_g1[col];
#pragma unroll
    for (int r = 0; r < 4; r++){
      g1s[(quad*4 + r)*GPAD + col]      = fmaxf(acc0[r] + bias, 0.f);
      g1s[(16 + quad*4 + r)*GPAD + col] = fmaxf(acc1[r] + bias, 0.f);
    }
  }
  __syncthreads();

  // ---- gate scalar + sigmoid (8 threads per token, 32 tokens) ----
  {
    int t = tid >> 3, part = tid & 7;
    const float* g1r = g1s + t*GPAD + part*8;
    const float* w2p = w2 + part*8;
    float s = 0.f;
#pragma unroll
    for (int j = 0; j < 8; j++) s += g1r[j] * w2p[j];
    s += __shfl_xor(s, 1);
    s += __shfl_xor(s, 2);
    s += __shfl_xor(s, 4);
    if (part == 0) gl[t] = 1.f / (1.f + __expf(-(s + b2[0])));
  }
  __syncthreads();
  // ---- softmax over views (4 l's) ----
  if (tid < 4){
    float v[8]; float mx = -1e30f;
    for (int n = 0; n < 8; n++){ v[n] = gl[tid*8+n]; mx = fmaxf(mx, v[n]); }
    float sum = 0.f;
    for (int n = 0; n < 8; n++){ v[n] = __expf(v[n]-mx); sum += v[n]; }
    float inv = 1.f/sum;
    for (int n = 0; n < 8; n++) wgt[tid*8+n] = v[n]*inv;
  }
  __syncthreads();

  // ---- fused = sum_n w_n * attended, then LayerNorm over C ----
  float f8[8];
  const int lfl = tid >> 5, ccf = tid & 31;   // lfl 0..3 valid (tid<128)
  if (tid < 128){
    float wloc[8];
#pragma unroll
    for (int n = 0; n < 8; n++) wloc[n] = wgt[lfl*8+n];
#pragma unroll
    for (int j = 0; j < 8; j++) f8[j] = 0.f;
#pragma unroll
    for (int n = 0; n < 8; n++){
      int row = lfl*8 + n;
      bf16x8 a8 = *(const bf16x8*)(att + row*256 + ((ccf ^ (row & 31)))*8);
      float aw = wloc[n];
#pragma unroll
      for (int j = 0; j < 8; j++) f8[j] += aw * bf2f(a8[j]);
    }
    float s = 0.f, s2 = 0.f;
#pragma unroll
    for (int j = 0; j < 8; j++){ s += f8[j]; s2 += f8[j]*f8[j]; }
    red1[lfl*32 + ccf] = s;
    red2[lfl*32 + ccf] = s2;
  }
  __syncthreads();
  if (tid < 4){
    float s = 0.f, s2 = 0.f;
    for (int i = 0; i < 32; i++){ s += red1[tid*32+i]; s2 += red2[tid*32+i]; }
    float mu = s * (1.f/256.f);
    float var = s2 * (1.f/256.f) - mu*mu;
    mus[tid] = mu;
    rvs[tid] = rsqrtf(var + 1e-5f);
  }
  __syncthreads();
  if (tid < 128){
    float mu = mus[lfl], rv = rvs[lfl];
    long lg = (long)blockIdx.x * TL + lfl;
    float* op = out + lg * C_DIM + ccf*8;
    float o8[8];
#pragma unroll
    for (int j = 0; j < 8; j++){
      int c = ccf*8 + j;
      o8[j] = (f8[j]-mu)*rv*ln_g[c] + ln_b[c];
    }
    *(float4*)(op)   = make_float4(o8[0],o8[1],o8[2],o8[3]);
    *(float4*)(op+4) = make_float4(o8[4],o8[5],o8[6],o8[7]);
  }
}

extern "C" void kernel_launch(void* const* d_in, const int* in_sizes, int n_in,
                              void* d_out, int out_size, void* d_ws, size_t ws_size,
                              hipStream_t stream){
  const float* feat  = (const float*)d_in[0];
  const float* vw    = (const float*)d_in[1];
  const float* vb    = (const float*)d_in[2];
  const float* w_in  = (const float*)d_in[3];
  const float* b_in  = (const float*)d_in[4];
  const float* w_out = (const float*)d_in[5];
  const float* b_out = (const float*)d_in[6];
  const float* w_g1  = (const float*)d_in[7];
  const float* b_g1  = (const float*)d_in[8];
  const float* w2    = (const float*)d_in[9];
  const float* b2    = (const float*)d_in[10];
  const float* lng   = (const float*)d_in[11];
  const float* lnb   = (const float*)d_in[12];

  char* ws = (char*)d_ws;
  float* view_info = (float*)ws;              //   8192 B
  short* win_hi  = (short*)(ws + 8192);       // 393216 B (packed)
  short* win_lo  = (short*)(ws + 401408);     // 393216 B (packed)
  short* wout_pk = (short*)(ws + 794624);     // 131072 B (packed)
  short* wg1_pk  = (short*)(ws + 925696);     //  32768 B (packed)  total 958464 B

  prep_kernel<<<64, 256, 0, stream>>>(vw, vb, w_in, w_out, w_g1,
                                      view_info, win_hi, win_lo, wout_pk, wg1_pk);
  fused_kernel<<<L_DIM/TL, NTHREADS, 34080, stream>>>(
      feat, view_info, win_hi, win_lo, wout_pk, wg1_pk,
      b_in, b_out, b_g1, w2, b2, lng, lnb, (float*)d_out);
}